// Round 2
// baseline (673.095 us; speedup 1.0000x reference)
//
#include <hip/hip_runtime.h>

// MLA forward. Inputs f32 (per reference), internal compute bf16 MFMA 16x16x32,
// output f32. R2: dtype fix only — pipeline structure unchanged from R1.

typedef __attribute__((ext_vector_type(8))) short short8;
typedef __attribute__((ext_vector_type(4))) float floatx4;
typedef unsigned short u16;
typedef unsigned int u32;

#define LOG2E 1.4426950408889634f

__device__ __forceinline__ float bf2f(u16 u){ u32 x=((u32)u)<<16; return __builtin_bit_cast(float,x); }
__device__ __forceinline__ u16 f2bf(float f){ u32 x=__builtin_bit_cast(u32,f); return (u16)((x + 0x7fffu + ((x>>16)&1u))>>16); }

__device__ __forceinline__ floatx4 mfma16(short8 a, short8 b, floatx4 c){
  return __builtin_amdgcn_mfma_f32_16x16x32_bf16(a,b,c,0,0,0);
}

// ---------- f32 -> bf16 elementwise (for x) ----------
__global__ __launch_bounds__(256)
void k_f2b(const float* __restrict__ in, u16* __restrict__ out, size_t n){
  size_t i = ((size_t)blockIdx.x*256 + threadIdx.x)*4;
  if(i >= n) return;
  float4 v = *(const float4*)(in + i);
  out[i+0] = f2bf(v.x); out[i+1] = f2bf(v.y); out[i+2] = f2bf(v.z); out[i+3] = f2bf(v.w);
}

// ---------- transpose + convert: f32 [K,N] -> bf16 [N,K] ----------
__global__ void k_transpose(const float* __restrict__ in, u16* __restrict__ out, int K, int N){
  __shared__ u16 tile[32][33];
  const int kb = blockIdx.y*32, nb = blockIdx.x*32;
  const int tx = threadIdx.x, ty = threadIdx.y;
#pragma unroll
  for(int i=0;i<4;i++) tile[ty+i*8][tx] = f2bf(in[(size_t)(kb+ty+i*8)*N + nb + tx]);
  __syncthreads();
#pragma unroll
  for(int i=0;i<4;i++) out[(size_t)(nb+ty+i*8)*K + kb + tx] = tile[tx][ty+i*8];
}

// ---------- rope table (fp64 for large-angle accuracy) ----------
__global__ void k_rope_table(float* __restrict__ cosT, float* __restrict__ sinT){
  int idx = blockIdx.x*256 + threadIdx.x;
  if(idx >= 2048*64) return;
  int p = idx>>6, i = idx&63;
  double freq = pow(10000.0, -(double)(2*i)/128.0) * 40.0;
  float ff = (float)freq;
  float ang = (float)((double)p * (double)ff);
  cosT[idx] = (float)cos((double)ang);
  sinT[idx] = (float)sin((double)ang);
}

// ---------- GEMM: A[M,K] bf16 @ Bt[N,K] bf16 -> C[M,N] (bf16 or f32) ----------
// 128x128 tile, BK=32, 256 threads (4 waves, 2x2 of 64x64), 4x4 MFMA frags/wave.
template<int OUTF32>
__global__ __launch_bounds__(256)
void k_gemm_bt(const u16* __restrict__ A, const u16* __restrict__ Bt, void* __restrict__ Cout,
               int M, int N, int K){
  __shared__ __align__(16) u16 lsA[128*32];
  __shared__ __align__(16) u16 lsB[128*32];
  const int t = threadIdx.x;
  const int m0 = blockIdx.y*128, n0 = blockIdx.x*128;
  const int wv = t>>6, ln = t&63;
  const int wr = (wv>>1)*64, wc = (wv&1)*64;
  const int fr = ln&15, kh = (ln>>4)*8;
  const u16* Ag = A + (size_t)(m0 + (t>>1))*K + (t&1)*16;
  const u16* Bg = Bt + (size_t)(n0 + (t>>1))*K + (t&1)*16;
  u16* lA = &lsA[(t>>1)*32 + (t&1)*16];
  u16* lB = &lsB[(t>>1)*32 + (t&1)*16];
  floatx4 acc[4][4];
#pragma unroll
  for(int i=0;i<4;i++)
#pragma unroll
    for(int j=0;j<4;j++) acc[i][j] = (floatx4){0.f,0.f,0.f,0.f};
  for(int k0=0;k0<K;k0+=32){
    uint4 a0 = *(const uint4*)(Ag + k0);
    uint4 a1 = *(const uint4*)(Ag + k0 + 8);
    uint4 b0 = *(const uint4*)(Bg + k0);
    uint4 b1 = *(const uint4*)(Bg + k0 + 8);
    __syncthreads();
    *(uint4*)lA = a0; *(uint4*)(lA+8) = a1;
    *(uint4*)lB = b0; *(uint4*)(lB+8) = b1;
    __syncthreads();
    short8 af[4], bf[4];
#pragma unroll
    for(int i=0;i<4;i++) af[i] = *(const short8*)&lsA[(wr + i*16 + fr)*32 + kh];
#pragma unroll
    for(int i=0;i<4;i++) bf[i] = *(const short8*)&lsB[(wc + i*16 + fr)*32 + kh];
#pragma unroll
    for(int mi=0;mi<4;mi++)
#pragma unroll
      for(int ni=0;ni<4;ni++) acc[mi][ni] = mfma16(af[mi], bf[ni], acc[mi][ni]);
  }
  const int r0 = (ln>>4)*4, c0 = ln&15;
#pragma unroll
  for(int mi=0;mi<4;mi++)
#pragma unroll
    for(int ni=0;ni<4;ni++){
      const int row = m0 + wr + mi*16 + r0;
      const int col = n0 + wc + ni*16 + c0;
#pragma unroll
      for(int r=0;r<4;r++){
        float v = acc[mi][ni][r];
        if(OUTF32) ((float*)Cout)[(size_t)(row+r)*N + col] = v;
        else       ((u16*)Cout)[(size_t)(row+r)*N + col] = f2bf(v);
      }
    }
}

// ---------- layernorm(kv[:512]) -> bf16 ; rope(kv[512:640]) -> k_pe bf16 ----------
__global__ __launch_bounds__(256)
void k_ln_rope(const float* __restrict__ kv, const float* __restrict__ scale,
               const int* __restrict__ pid, const float* __restrict__ cosT,
               const float* __restrict__ sinT, u16* __restrict__ kv_cn, u16* __restrict__ k_pe){
  const int tok = blockIdx.x;
  const int t = threadIdx.x;
  const float* row = kv + (size_t)tok*640;
  float v0 = row[2*t], v1 = row[2*t+1];
  float s = v0+v1, ss = v0*v0+v1*v1;
#pragma unroll
  for(int off=32; off>=1; off>>=1){ s += __shfl_xor(s,off); ss += __shfl_xor(ss,off); }
  __shared__ float red[8];
  if((t&63)==0){ red[t>>6]=s; red[4+(t>>6)]=ss; }
  __syncthreads();
  float S4 = red[0]+red[1]+red[2]+red[3];
  float SS4 = red[4]+red[5]+red[6]+red[7];
  float mean = S4*(1.f/512.f);
  float var = SS4*(1.f/512.f) - mean*mean;
  float inv = rsqrtf(var + 1e-5f);
  kv_cn[(size_t)tok*512 + 2*t]   = f2bf((v0-mean)*inv*scale[2*t]);
  kv_cn[(size_t)tok*512 + 2*t+1] = f2bf((v1-mean)*inv*scale[2*t+1]);
  if(t < 128){
    const int sidx = tok & 2047;
    const int p = pid[sidx];
    const int i = t>>1;
    float c = cosT[p*64+i], sn = sinT[p*64+i];
    float xr = row[512+2*i], xi = row[512+2*i+1];
    float val = (t&1) ? (xr*sn + xi*c) : (xr*c - xi*sn);
    k_pe[(size_t)tok*128 + t] = f2bf(val);
  }
}

// ---------- q: copy nope, rope pe; layout [B,H,S,256] ----------
__global__ __launch_bounds__(256)
void k_q_rope(const u16* __restrict__ q_raw, const int* __restrict__ pid,
              const float* __restrict__ cosT, const float* __restrict__ sinT,
              u16* __restrict__ q_fin){
  const int tok = blockIdx.x;
  const int b = tok>>11, sidx = tok&2047;
  const int t = threadIdx.x;
  const int p = pid[sidx];
  for(int h=0; h<16; h++){
    const u16* src = q_raw + (size_t)tok*4096 + h*256;
    float val;
    if(t < 128) val = bf2f(src[t]);
    else {
      int d = t-128, i = d>>1;
      float c = cosT[p*64+i], sn = sinT[p*64+i];
      float xr = bf2f(src[128+2*i]), xi = bf2f(src[128+2*i+1]);
      val = (d&1) ? (xr*sn + xi*c) : (xr*c - xi*sn);
    }
    q_fin[(((size_t)(b*16 + h))*2048 + sidx)*256 + t] = f2bf(val);
  }
}

// ---------- k_full[b][kvh][s][256] = concat(k_nope, k_pe) ----------
__global__ __launch_bounds__(256)
void k_build_k(const u16* __restrict__ kvb, const u16* __restrict__ k_pe, u16* __restrict__ k_full){
  const int tok = blockIdx.x;
  const int b = tok>>11, sidx = tok&2047;
  const int t = threadIdx.x;
  for(int kh=0; kh<8; kh++){
    u16 v = (t<128) ? kvb[(size_t)tok*2048 + kh*256 + t]
                    : k_pe[(size_t)tok*128 + (t-128)];
    k_full[(((size_t)(b*8 + kh))*2048 + sidx)*256 + t] = v;
  }
}

// ---------- v_t[b][kvh][hd][s] from kvb v-part ----------
__global__ void k_v_t(const u16* __restrict__ kvb, u16* __restrict__ v_t){
  __shared__ u16 tile[32][33];
  const int sb = blockIdx.x*32, hb = blockIdx.y*32;
  const int bk = blockIdx.z;
  const int b = bk>>3, kh = bk&7;
  const int tx = threadIdx.x, ty = threadIdx.y;
#pragma unroll
  for(int i=0;i<4;i++){
    int sidx = sb + ty + i*8;
    tile[ty+i*8][tx] = kvb[((size_t)(b*2048 + sidx))*2048 + kh*256 + 128 + hb + tx];
  }
  __syncthreads();
#pragma unroll
  for(int i=0;i<4;i++){
    int hd = hb + ty + i*8;
    v_t[((size_t)bk*128 + hd)*2048 + sb + tx] = tile[tx][ty+i*8];
  }
}

// ---------- flash attention: 64-row Q tile/block, 64-col KV tiles ----------
__global__ __launch_bounds__(256)
void k_attn(const u16* __restrict__ q_fin, const u16* __restrict__ k_full,
            const u16* __restrict__ v_t, u16* __restrict__ attn){
  __shared__ __align__(16) u16 lsK[64*264];   // 256 + 8 pad
  __shared__ __align__(16) u16 lsV[128*72];   // 64 + 8 pad
  __shared__ __align__(16) u16 lsP[4*16*72];  // per-wave P, padded
  const int qt = blockIdx.x, h = blockIdx.y, b = blockIdx.z;
  const int kvh = h>>1;
  const int t = threadIdx.x, wv = t>>6, ln = t&63;
  const int fr = ln&15, g = ln>>4;

  short8 qf[8];
  const u16* qbase = q_fin + (((size_t)(b*16 + h))*2048 + qt*64 + wv*16 + fr)*256;
#pragma unroll
  for(int c=0;c<8;c++) qf[c] = *(const short8*)(qbase + c*32 + g*8);

  floatx4 oacc[8];
#pragma unroll
  for(int i=0;i<8;i++) oacc[i] = (floatx4){0.f,0.f,0.f,0.f};
  float mprev[4] = {-3e38f,-3e38f,-3e38f,-3e38f};
  float lsum[4] = {0.f,0.f,0.f,0.f};

  const u16* kbase = k_full + ((size_t)(b*8 + kvh))*2048*256;
  const u16* vbase = v_t + ((size_t)(b*8 + kvh))*128*2048;
  const int qi0 = qt*64 + wv*16 + g*4;

  for(int kt=0; kt<=qt; kt++){
#pragma unroll
    for(int i=0;i<8;i++){
      int c = t + i*256, row = c>>5, col = (c&31)*8;
      *(uint4*)&lsK[row*264 + col] = *(const uint4*)(kbase + (size_t)(kt*64+row)*256 + col);
    }
#pragma unroll
    for(int i=0;i<4;i++){
      int c = t + i*256, row = c>>3, col = (c&7)*8;
      *(uint4*)&lsV[row*72 + col] = *(const uint4*)(vbase + (size_t)row*2048 + kt*64 + col);
    }
    __syncthreads();

    floatx4 sc[4];
#pragma unroll
    for(int ns=0;ns<4;ns++) sc[ns] = (floatx4){0.f,0.f,0.f,0.f};
#pragma unroll
    for(int ns=0;ns<4;ns++){
      const u16* kr = &lsK[(ns*16 + fr)*264 + g*8];
#pragma unroll
      for(int c=0;c<8;c++){
        short8 kf = *(const short8*)(kr + c*32);
        sc[ns] = mfma16(qf[c], kf, sc[ns]);
      }
    }

    float mloc[4];
#pragma unroll
    for(int r=0;r<4;r++){
      const int qi = qi0 + r;
      float mm = -3e38f;
#pragma unroll
      for(int ns=0;ns<4;ns++){
        const int kvi = kt*64 + ns*16 + fr;
        float v = sc[ns][r]*0.08838834764831845f;
        if(kvi > qi) v = -1e9f;
        sc[ns][r] = v;
        mm = fmaxf(mm, v);
      }
      mloc[r] = mm;
    }
#pragma unroll
    for(int off=1; off<16; off<<=1){
#pragma unroll
      for(int r=0;r<4;r++) mloc[r] = fmaxf(mloc[r], __shfl_xor(mloc[r], off));
    }
    float alpha[4], psum[4];
#pragma unroll
    for(int r=0;r<4;r++){
      const float mn = fmaxf(mprev[r], mloc[r]);
      alpha[r] = exp2f((mprev[r]-mn)*LOG2E);
      float ps = 0.f;
#pragma unroll
      for(int ns=0;ns<4;ns++){
        float p = exp2f((sc[ns][r]-mn)*LOG2E);
        sc[ns][r] = p;
        ps += p;
      }
      mprev[r] = mn;
      psum[r] = ps;
    }
#pragma unroll
    for(int off=1; off<16; off<<=1){
#pragma unroll
      for(int r=0;r<4;r++) psum[r] += __shfl_xor(psum[r], off);
    }
#pragma unroll
    for(int r=0;r<4;r++) lsum[r] = lsum[r]*alpha[r] + psum[r];

    u16* pw = &lsP[wv*1152];
#pragma unroll
    for(int ns=0;ns<4;ns++)
#pragma unroll
      for(int r=0;r<4;r++) pw[(g*4+r)*72 + ns*16 + fr] = f2bf(sc[ns][r]);
#pragma unroll
    for(int j=0;j<8;j++)
#pragma unroll
      for(int r=0;r<4;r++) oacc[j][r] *= alpha[r];
    __syncthreads();  // P visible + lsV reads below ordered vs writes

#pragma unroll
    for(int kc=0;kc<2;kc++){
      short8 pa = *(const short8*)&lsP[(wv*16 + fr)*72 + kc*32 + g*8];
#pragma unroll
      for(int hs=0;hs<8;hs++){
        short8 vb = *(const short8*)&lsV[(hs*16 + fr)*72 + kc*32 + g*8];
        oacc[hs] = mfma16(pa, vb, oacc[hs]);
      }
    }
    __syncthreads();  // protect lsK/lsV before next stage
  }
  float inv[4];
#pragma unroll
  for(int r=0;r<4;r++) inv[r] = 1.f / lsum[r];
#pragma unroll
  for(int hs=0;hs<8;hs++)
#pragma unroll
    for(int r=0;r<4;r++){
      const int qi = qi0 + r;
      attn[(((size_t)(b*2048 + qi))*16 + h)*128 + hs*16 + fr] = f2bf(oacc[hs][r]*inv[r]);
    }
}

extern "C" void kernel_launch(void* const* d_in, const int* in_sizes, int n_in,
                              void* d_out, int out_size, void* d_ws, size_t ws_size,
                              hipStream_t stream){
  const float* x    = (const float*)d_in[0];
  const float* wq   = (const float*)d_in[1];
  const float* wkva = (const float*)d_in[2];
  const float* kvsc = (const float*)d_in[3];
  const float* wkvb = (const float*)d_in[4];
  const float* wo   = (const float*)d_in[5];
  // d_in[6]: attention_mask (pure causal — applied analytically)
  const int* pid  = (const int*)d_in[7];
  float* out = (float*)d_out;

  char* w = (char*)d_ws;
  size_t off = 0;
  auto alloc = [&](size_t bytes)->void*{
    void* p = (void*)(w + off);
    off += (bytes + 255) & ~(size_t)255;
    return p;
  };
  u16*   x_bf   = (u16*)alloc((size_t)4096*2048*2);
  u16*   wq_t   = (u16*)alloc((size_t)4096*2048*2);
  u16*   wkva_t = (u16*)alloc((size_t)640*2048*2);
  u16*   wkvb_t = (u16*)alloc((size_t)2048*512*2);
  u16*   wo_t   = (u16*)alloc((size_t)2048*2048*2);
  float* cosT   = (float*)alloc((size_t)2048*64*4);
  float* sinT   = (float*)alloc((size_t)2048*64*4);
  u16*   q_raw  = (u16*)alloc((size_t)4096*4096*2);
  float* kvf    = (float*)alloc((size_t)4096*640*4);
  u16*   kv_cn  = (u16*)alloc((size_t)4096*512*2);
  u16*   k_pe   = (u16*)alloc((size_t)4096*128*2);
  u16*   kvb    = (u16*)alloc((size_t)4096*2048*2);
  u16*   q_fin  = (u16*)alloc((size_t)4096*4096*2);
  u16*   k_full = (u16*)alloc((size_t)2*8*2048*256*2);
  u16*   v_t    = (u16*)alloc((size_t)2*8*128*2048*2);
  u16*   attn   = (u16*)alloc((size_t)4096*2048*2);

  k_f2b<<<8192, 256, 0, stream>>>(x, x_bf, (size_t)4096*2048);
  k_transpose<<<dim3(128, 64), dim3(32,8), 0, stream>>>(wq,   wq_t,   2048, 4096);
  k_transpose<<<dim3(20,  64), dim3(32,8), 0, stream>>>(wkva, wkva_t, 2048, 640);
  k_transpose<<<dim3(64,  16), dim3(32,8), 0, stream>>>(wkvb, wkvb_t, 512,  2048);
  k_transpose<<<dim3(64,  64), dim3(32,8), 0, stream>>>(wo,   wo_t,   2048, 2048);
  k_rope_table<<<512, 256, 0, stream>>>(cosT, sinT);

  k_gemm_bt<0><<<dim3(32, 32), 256, 0, stream>>>(x_bf, wq_t, q_raw, 4096, 4096, 2048);
  k_gemm_bt<1><<<dim3(5,  32), 256, 0, stream>>>(x_bf, wkva_t, kvf, 4096, 640, 2048);
  k_ln_rope<<<4096, 256, 0, stream>>>(kvf, kvsc, pid, cosT, sinT, kv_cn, k_pe);
  k_gemm_bt<0><<<dim3(16, 32), 256, 0, stream>>>(kv_cn, wkvb_t, kvb, 4096, 2048, 512);
  k_q_rope<<<4096, 256, 0, stream>>>(q_raw, pid, cosT, sinT, q_fin);
  k_build_k<<<4096, 256, 0, stream>>>(kvb, k_pe, k_full);
  k_v_t<<<dim3(64, 4, 16), dim3(32,8), 0, stream>>>(kvb, v_t);
  k_attn<<<dim3(32, 16, 2), 256, 0, stream>>>(q_fin, k_full, v_t, attn);
  k_gemm_bt<1><<<dim3(16, 32), 256, 0, stream>>>(attn, wo_t, out, 4096, 2048, 2048);
}